// Round 4
// baseline (116.470 us; speedup 1.0000x reference)
//
#include <hip/hip_runtime.h>
#include <hip/hip_bf16.h>

// CFAR via full 2D summed-area table (SAT), hierarchical column prefix.
// out = SCALE * front / (allsum - front),  SCALE = BG_AREA / FRONT_DIV
// front  = 161x161 box sum = 4 SAT corners (+80 / -81)
// allsum = 321x321 box sum = 4 SAT corners (+160 / -161)
// BG_AREA = 321^2-161^2 = 77120 ; FRONT_DIV = 161^2*1.8 = 46657.8
//
// S layout: [img][row][WP] fp32, WP=1280: cols [0,1024) = row prefix,
// cols [1024,1280) = row total (right clamp pad). Left clamp (col<0 -> 0)
// handled by masked scalar loads in the final kernel.

#define IMG 4
#define H 1024
#define W 1024
#define WP 1280
#define NSEG 32
#define SEGR 32

// ---------- Kernel 1: row prefix (no LDS, no barrier) ----------
// One wave per row: 4x float4 load, intra-lane scan, wave shuffle scan,
// store 4 quads of prefix + 1 quad of row-total pad.
__global__ __launch_bounds__(256) void hprefix_kernel(const float* __restrict__ x,
                                                      float* __restrict__ S) {
    const int wave = threadIdx.x >> 6;
    const int lane = threadIdx.x & 63;
    const int row  = (blockIdx.x << 2) + wave;   // 0..4095 flat over images

    const float4* xr = reinterpret_cast<const float4*>(x + (size_t)row * W);
    float v[16];
    {
        float4 a0 = xr[(lane << 2) + 0];
        float4 a1 = xr[(lane << 2) + 1];
        float4 a2 = xr[(lane << 2) + 2];
        float4 a3 = xr[(lane << 2) + 3];
        v[0]=a0.x; v[1]=a0.y; v[2]=a0.z; v[3]=a0.w;
        v[4]=a1.x; v[5]=a1.y; v[6]=a1.z; v[7]=a1.w;
        v[8]=a2.x; v[9]=a2.y; v[10]=a2.z; v[11]=a2.w;
        v[12]=a3.x; v[13]=a3.y; v[14]=a3.z; v[15]=a3.w;
    }
    float s = 0.f;
#pragma unroll
    for (int j = 0; j < 16; ++j) { s += v[j]; v[j] = s; }
    float t = s;
#pragma unroll
    for (int d = 1; d < 64; d <<= 1) {
        float u = __shfl_up(t, d, 64);
        if (lane >= d) t += u;
    }
    const float off = t - s;           // exclusive prefix of lane totals
#pragma unroll
    for (int j = 0; j < 16; ++j) v[j] += off;
    const float tot = __shfl(t, 63, 64);

    float4* Sr = reinterpret_cast<float4*>(S + (size_t)row * WP);
    Sr[(lane << 2) + 0] = make_float4(v[0], v[1], v[2], v[3]);
    Sr[(lane << 2) + 1] = make_float4(v[4], v[5], v[6], v[7]);
    Sr[(lane << 2) + 2] = make_float4(v[8], v[9], v[10], v[11]);
    Sr[(lane << 2) + 3] = make_float4(v[12], v[13], v[14], v[15]);
    Sr[256 + lane]      = make_float4(tot, tot, tot, tot);   // quads 256..319
}

// ---------- Kernel 2: per-segment column prefix (in place) + seg totals ----
// grid = img(4) x seg(32) x colblk(5) = 640 blocks, 256 threads (1 col each).
__global__ __launch_bounds__(256) void vscan_kernel(float* __restrict__ S,
                                                    float* __restrict__ Btot) {
    const int bx  = blockIdx.x;
    const int img = bx / 160;          // 160 = 32*5
    const int rem = bx - img * 160;
    const int seg = rem / 5;
    const int cb  = rem - seg * 5;
    const int col = (cb << 8) + threadIdx.x;

    float* p = S + ((size_t)img * H + (size_t)seg * SEGR) * WP + col;
    float sum = 0.f;
#pragma unroll
    for (int jj = 0; jj < SEGR; jj += 8) {
        float a[8];
#pragma unroll
        for (int j = 0; j < 8; ++j) a[j] = p[(size_t)(jj + j) * WP];
#pragma unroll
        for (int j = 0; j < 8; ++j) { sum += a[j]; a[j] = sum; }
#pragma unroll
        for (int j = 0; j < 8; ++j) p[(size_t)(jj + j) * WP] = a[j];
    }
    Btot[((size_t)img * NSEG + seg) * WP + col] = sum;
}

// ---------- Kernel 3: exclusive scan of segment totals per column ----------
// 4 imgs x 1280 cols = 5120 threads = 20 blocks x 256.
__global__ __launch_bounds__(256) void segscan_kernel(const float* __restrict__ Btot,
                                                      float* __restrict__ SP) {
    const int t   = blockIdx.x * 256 + threadIdx.x;
    const int img = t / WP;
    const int col = t - img * WP;
    const float* b = Btot + (size_t)img * NSEG * WP + col;
    float*     sp = SP   + (size_t)img * NSEG * WP + col;
    float off = 0.f;
#pragma unroll
    for (int sg = 0; sg < NSEG; ++sg) {
        const float v = b[(size_t)sg * WP];
        sp[(size_t)sg * WP] = off;
        off += v;
    }
}

// ---------- Kernel 4: final — 8 SAT corners per window pair + math ---------
// One block per (img,row), thread = one float4 column group.
__global__ __launch_bounds__(256) void final_kernel(const float* __restrict__ S,
                                                    const float* __restrict__ SP,
                                                    float* __restrict__ out) {
    const int img = blockIdx.x >> 10;
    const int r   = blockIdx.x & 1023;
    const int c4  = threadIdx.x;          // 0..255
    const int cb  = c4 << 2;

    const float* Si  = S  + (size_t)img * H * WP;
    const float* SPi = SP + (size_t)img * NSEG * WP;

    const int R3h = min(r + 160, H - 1), R3l = r - 161;
    const int R1h = min(r + 80,  H - 1), R1l = r - 81;
    const int CH3 = cb + 160, CH1 = cb + 80;   // aligned, < WP

    // aligned quad of full column prefix P(row, c..c+3)
#define P4(row, c) ({                                                          \
        const float4 _a = *reinterpret_cast<const float4*>(Si + (size_t)(row) * WP + (c));   \
        const float4 _b = *reinterpret_cast<const float4*>(SPi + (size_t)((row) >> 5) * WP + (c)); \
        make_float4(_a.x + _b.x, _a.y + _b.y, _a.z + _b.z, _a.w + _b.w); })

    float ax, ay, az, aw, fx, fy, fz, fw;
    {
        const float4 A = P4(R3h, CH3);
        float lo[4];
#pragma unroll
        for (int i = 0; i < 4; ++i) {
            const int c = cb + i - 161;
            lo[i] = (c >= 0) ? (Si[(size_t)R3h * WP + c] + SPi[(size_t)(R3h >> 5) * WP + c]) : 0.f;
        }
        ax = A.x - lo[0]; ay = A.y - lo[1]; az = A.z - lo[2]; aw = A.w - lo[3];
    }
    if (R3l >= 0) {   // block-uniform branch
        const float4 B = P4(R3l, CH3);
        float lo[4];
#pragma unroll
        for (int i = 0; i < 4; ++i) {
            const int c = cb + i - 161;
            lo[i] = (c >= 0) ? (Si[(size_t)R3l * WP + c] + SPi[(size_t)(R3l >> 5) * WP + c]) : 0.f;
        }
        ax -= B.x - lo[0]; ay -= B.y - lo[1]; az -= B.z - lo[2]; aw -= B.w - lo[3];
    }
    {
        const float4 Fq = P4(R1h, CH1);
        float lo[4];
#pragma unroll
        for (int i = 0; i < 4; ++i) {
            const int c = cb + i - 81;
            lo[i] = (c >= 0) ? (Si[(size_t)R1h * WP + c] + SPi[(size_t)(R1h >> 5) * WP + c]) : 0.f;
        }
        fx = Fq.x - lo[0]; fy = Fq.y - lo[1]; fz = Fq.z - lo[2]; fw = Fq.w - lo[3];
    }
    if (R1l >= 0) {   // block-uniform branch
        const float4 G = P4(R1l, CH1);
        float lo[4];
#pragma unroll
        for (int i = 0; i < 4; ++i) {
            const int c = cb + i - 81;
            lo[i] = (c >= 0) ? (Si[(size_t)R1l * WP + c] + SPi[(size_t)(R1l >> 5) * WP + c]) : 0.f;
        }
        fx -= G.x - lo[0]; fy -= G.y - lo[1]; fz -= G.z - lo[2]; fw -= G.w - lo[3];
    }
#undef P4

    const float SCALE = (float)(77120.0 / 46657.8);   // BG_AREA / FRONT_DIV
    float4 o;
    o.x = SCALE * fx / (ax - fx);
    o.y = SCALE * fy / (ay - fy);
    o.z = SCALE * fz / (az - fz);
    o.w = SCALE * fw / (aw - fw);
    reinterpret_cast<float4*>(out + ((size_t)img << 20) + ((size_t)r << 10))[c4] = o;
}

extern "C" void kernel_launch(void* const* d_in, const int* in_sizes, int n_in,
                              void* d_out, int out_size, void* d_ws, size_t ws_size,
                              hipStream_t stream) {
    const float* x = (const float*)d_in[0];
    float* outp = (float*)d_out;
    float* S    = (float*)d_ws;                             // 4*1024*1280*4 = 20.97 MB
    float* Btot = S + (size_t)IMG * H * WP;                 // 4*32*1280*4 = 655 KB
    float* SPb  = Btot + (size_t)IMG * NSEG * WP;           // 655 KB

    hprefix_kernel<<<dim3((IMG * H) / 4), dim3(256), 0, stream>>>(x, S);
    vscan_kernel<<<dim3(IMG * NSEG * 5), dim3(256), 0, stream>>>(S, Btot);
    segscan_kernel<<<dim3(20), dim3(256), 0, stream>>>(Btot, SPb);
    final_kernel<<<dim3(IMG * H), dim3(256), 0, stream>>>(S, SPb, outp);
}

// Round 5
// 100.006 us; speedup vs baseline: 1.1646x; 1.1646x over previous
//
#include <hip/hip_runtime.h>
#include <hip/hip_bf16.h>

// CFAR via separable box sums. Structure:
//   hseg : row prefix (LDS, padded) -> horizontal window diffs (161/321) ->
//          per-8-row-segment vertical inclusive scan, written to g161/g321,
//          plus segment totals Btot.           [fused hbox+vscan]
//   segscan : exclusive scan of 128 segment totals per column -> SP
//   final : front = P(r+80)-P(r-81), allsum = P(r+160)-P(r-161),
//           P(rho) = g[rho] + SP[rho>>3] ; out = SCALE*front/(allsum-front)
// BG_AREA = 321^2-161^2 = 77120 ; FRONT_DIV = 161^2*1.8 = 46657.8

#define IMG 4
#define H 1024
#define W 1024
#define SEGR 8
#define NSEG 128                    // H / SEGR
#define PADL 164
#define PADR 164
#define ROWLEN (PADL + W + PADR)    // 1352 floats; row stride 5408 B (16B-mult)

// ---------------- Kernel 1: fused horizontal + segment vertical scan -------
// Block = (img, seg): 8 rows x 1024 cols. 256 threads.
// Phase 1: wave w computes prefix of local rows 2w, 2w+1 into padded LDS
//          (left pad = 0, right pad = row total -> clamp-free phase 2).
// Phase 2: thread owns quad c4; for each of 8 rows does 6 aligned
//          ds_read_b128, accumulates vertical prefix, stores scanned quads.
__global__ __launch_bounds__(256) void hseg_kernel(const float* __restrict__ x,
                                                   float* __restrict__ g161,
                                                   float* __restrict__ g321,
                                                   float* __restrict__ Btot) {
    __shared__ float P[SEGR][ROWLEN];   // 8*1352*4 = 43264 B
    const int wave = threadIdx.x >> 6;
    const int lane = threadIdx.x & 63;
    const int img  = blockIdx.x >> 7;
    const int seg  = blockIdx.x & 127;
    const int r0   = seg << 3;

    // ---- phase 1 ----
    {
        const int j0 = wave << 1;
        const float4* xr0 = reinterpret_cast<const float4*>(
            x + (((size_t)img << 10) + r0 + j0) * W);
        const float4* xr1 = reinterpret_cast<const float4*>(
            x + (((size_t)img << 10) + r0 + j0 + 1) * W);
        float4 a[2][4];
#pragma unroll
        for (int q = 0; q < 4; ++q) a[0][q] = xr0[(lane << 2) + q];
#pragma unroll
        for (int q = 0; q < 4; ++q) a[1][q] = xr1[(lane << 2) + q];

#pragma unroll
        for (int rr = 0; rr < 2; ++rr) {
            float v[16];
            v[0]=a[rr][0].x; v[1]=a[rr][0].y; v[2]=a[rr][0].z; v[3]=a[rr][0].w;
            v[4]=a[rr][1].x; v[5]=a[rr][1].y; v[6]=a[rr][1].z; v[7]=a[rr][1].w;
            v[8]=a[rr][2].x; v[9]=a[rr][2].y; v[10]=a[rr][2].z; v[11]=a[rr][2].w;
            v[12]=a[rr][3].x; v[13]=a[rr][3].y; v[14]=a[rr][3].z; v[15]=a[rr][3].w;
            float s = 0.f;
#pragma unroll
            for (int j = 0; j < 16; ++j) { s += v[j]; v[j] = s; }
            float t = s;
#pragma unroll
            for (int d = 1; d < 64; d <<= 1) {
                float u = __shfl_up(t, d, 64);
                if (lane >= d) t += u;
            }
            const float off = t - s;          // exclusive prefix of lane totals
#pragma unroll
            for (int j = 0; j < 16; ++j) v[j] += off;
            const float tot = __shfl(t, 63, 64);

            float* row = P[j0 + rr];
            float4* Pr = reinterpret_cast<float4*>(row + PADL);
            Pr[(lane << 2) + 0] = make_float4(v[0], v[1], v[2], v[3]);
            Pr[(lane << 2) + 1] = make_float4(v[4], v[5], v[6], v[7]);
            Pr[(lane << 2) + 2] = make_float4(v[8], v[9], v[10], v[11]);
            Pr[(lane << 2) + 3] = make_float4(v[12], v[13], v[14], v[15]);
            // pads: quads 0..40 = 0 (left), quads 297..337 = tot (right)
            float4* Pz = reinterpret_cast<float4*>(row);
            if (lane < 41) {
                Pz[lane]       = make_float4(0.f, 0.f, 0.f, 0.f);
                Pz[297 + lane] = make_float4(tot, tot, tot, tot);
            }
        }
    }
    __syncthreads();

    // ---- phase 2 ----
    const int c4 = threadIdx.x;            // quad column 0..255
    const int q  = PADL + (c4 << 2);       // padded float offset, %4 == 0
    float s1x=0.f,s1y=0.f,s1z=0.f,s1w=0.f;
    float s3x=0.f,s3y=0.f,s3z=0.f,s3w=0.f;
    float4* o1 = reinterpret_cast<float4*>(g161 + (((size_t)img << 10) + r0) * W) + c4;
    float4* o3 = reinterpret_cast<float4*>(g321 + (((size_t)img << 10) + r0) * W) + c4;

#pragma unroll
    for (int j = 0; j < SEGR; ++j) {
        const float* Pb = P[j];
        const float4 hi1 = *reinterpret_cast<const float4*>(&Pb[q + 80]);
        const float4 A   = *reinterpret_cast<const float4*>(&Pb[q - 84]);
        const float4 Bv  = *reinterpret_cast<const float4*>(&Pb[q - 80]);
        const float4 hi3 = *reinterpret_cast<const float4*>(&Pb[q + 160]);
        const float4 C   = *reinterpret_cast<const float4*>(&Pb[q - 164]);
        const float4 D   = *reinterpret_cast<const float4*>(&Pb[q - 160]);
        s1x += hi1.x - A.w;  s1y += hi1.y - Bv.x;
        s1z += hi1.z - Bv.y; s1w += hi1.w - Bv.z;
        s3x += hi3.x - C.w;  s3y += hi3.y - D.x;
        s3z += hi3.z - D.y;  s3w += hi3.w - D.z;
        o1[(size_t)j << 8] = make_float4(s1x, s1y, s1z, s1w);
        o3[(size_t)j << 8] = make_float4(s3x, s3y, s3z, s3w);
    }
    // segment totals: layout [buf][img][seg][W]
    float4* b1 = reinterpret_cast<float4*>(Btot + ((size_t)img * NSEG + seg) * W);
    float4* b3 = reinterpret_cast<float4*>(Btot + ((size_t)(IMG + img) * NSEG + seg) * W);
    b1[c4] = make_float4(s1x, s1y, s1z, s1w);
    b3[c4] = make_float4(s3x, s3y, s3z, s3w);
}

// ---------- Kernel 2: exclusive scan of segment totals per column ----------
// 2 bufs x 4 imgs x 1024 cols = 8192 threads = 32 blocks x 256.
__global__ __launch_bounds__(256) void segscan_kernel(const float* __restrict__ Btot,
                                                      float* __restrict__ SP) {
    const int t = blockIdx.x * 256 + threadIdx.x;     // (buf*IMG+img)*1024 + col
    const size_t base = ((size_t)(t >> 10) * NSEG) * W + (t & 1023);
    const float* b = Btot + base;
    float* sp = SP + base;
    float off = 0.f;
#pragma unroll 8
    for (int sg = 0; sg < NSEG; ++sg) {
        const float v = b[(size_t)sg << 10];
        sp[(size_t)sg << 10] = off;
        off += v;
    }
}

// ---------- Kernel 3: final — window diffs of full column prefixes ---------
// One block per (img,row); thread = one float4 column group.
__global__ __launch_bounds__(256) void final_kernel(const float* __restrict__ g161,
                                                    const float* __restrict__ g321,
                                                    const float* __restrict__ SP,
                                                    float* __restrict__ out) {
    const int img = blockIdx.x >> 10;
    const int r   = blockIdx.x & 1023;
    const int c4  = threadIdx.x;                      // 0..255

    const float4* P1 = reinterpret_cast<const float4*>(g161 + ((size_t)img << 20));
    const float4* P3 = reinterpret_cast<const float4*>(g321 + ((size_t)img << 20));
    // SP float4 layout: [buf][img][NSEG][256] ; NSEG*256 = 1<<15 per (buf,img)
    const float4* SP1 = reinterpret_cast<const float4*>(SP) + ((size_t)img << 15);
    const float4* SP3 = reinterpret_cast<const float4*>(SP) + ((size_t)(IMG + img) << 15);

    const int hi1 = min(r + 80, H - 1),  lo1 = r - 81;
    const int hi3 = min(r + 160, H - 1), lo3 = r - 161;

    float4 f  = P1[((size_t)hi1 << 8) + c4];
    float4 fs = SP1[(((size_t)hi1 >> 3) << 8) + c4];
    float fx = f.x + fs.x, fy = f.y + fs.y, fz = f.z + fs.z, fw = f.w + fs.w;
    if (lo1 >= 0) {   // block-uniform branch
        float4 g  = P1[((size_t)lo1 << 8) + c4];
        float4 gs = SP1[(((size_t)lo1 >> 3) << 8) + c4];
        fx -= g.x + gs.x; fy -= g.y + gs.y; fz -= g.z + gs.z; fw -= g.w + gs.w;
    }
    float4 a  = P3[((size_t)hi3 << 8) + c4];
    float4 as = SP3[(((size_t)hi3 >> 3) << 8) + c4];
    float ax = a.x + as.x, ay = a.y + as.y, az = a.z + as.z, aw = a.w + as.w;
    if (lo3 >= 0) {   // block-uniform branch
        float4 g  = P3[((size_t)lo3 << 8) + c4];
        float4 gs = SP3[(((size_t)lo3 >> 3) << 8) + c4];
        ax -= g.x + gs.x; ay -= g.y + gs.y; az -= g.z + gs.z; aw -= g.w + gs.w;
    }

    const float SCALE = (float)(77120.0 / 46657.8);   // BG_AREA / FRONT_DIV
    float4 o;
    o.x = SCALE * fx / (ax - fx);
    o.y = SCALE * fy / (ay - fy);
    o.z = SCALE * fz / (az - fz);
    o.w = SCALE * fw / (aw - fw);
    reinterpret_cast<float4*>(out + ((size_t)img << 20) + ((size_t)r << 10))[c4] = o;
}

extern "C" void kernel_launch(void* const* d_in, const int* in_sizes, int n_in,
                              void* d_out, int out_size, void* d_ws, size_t ws_size,
                              hipStream_t stream) {
    const float* x = (const float*)d_in[0];
    float* outp = (float*)d_out;
    float* g161 = (float*)d_ws;                               // 16 MB
    float* g321 = g161 + (size_t)IMG * H * W;                 // 16 MB
    float* Btot = g321 + (size_t)IMG * H * W;                 // 2*4*128*1024*4 = 4 MB
    float* SPb  = Btot + (size_t)2 * IMG * NSEG * W;          // 4 MB

    hseg_kernel<<<dim3(IMG * NSEG), dim3(256), 0, stream>>>(x, g161, g321, Btot);
    segscan_kernel<<<dim3(32), dim3(256), 0, stream>>>(Btot, SPb);
    final_kernel<<<dim3(IMG * H), dim3(256), 0, stream>>>(g161, g321, SPb, outp);
}

// Round 6
// 95.303 us; speedup vs baseline: 1.2221x; 1.0493x over previous
//
#include <hip/hip_runtime.h>
#include <hip/hip_bf16.h>

// CFAR via separable box sums (R3 structure, R1-style scalar phase-2 in hbox).
//   hbox    : row prefix (padded LDS) -> horizontal 161/321 window diffs
//   vscan   : in-place per-32-row-segment vertical inclusive scan + seg totals
//   segscan : exclusive scan of 32 segment totals per column -> SP
//   final   : front = P(r+80)-P(r-81), allsum = P(r+160)-P(r-161),
//             P(rho) = g[rho] + SP[rho>>5] ; out = SCALE*front/(allsum-front)
// BG_AREA = 321^2-161^2 = 77120 ; FRONT_DIV = 161^2*1.8 = 46657.8

#define IMG 4
#define H 1024
#define W 1024
#define NSEG 32
#define SEGR 32
#define PADL 164
#define PADR 164
#define ROWLEN (PADL + W + PADR)   // 1352 floats per padded LDS row

// ---------------- Kernel 1: horizontal box sums (both widths) ---------------
// One wave per row. Padded prefix row in LDS (left pad = 0, right pad = row
// total) -> clamp-free phase 2. Phase 2 = R1-proven scalar pattern:
// stride-64 column ownership, lane-stride-1 scalar LDS reads (2-way aliasing,
// free), scalar coalesced global stores.
__global__ __launch_bounds__(256) void hbox_kernel(const float* __restrict__ x,
                                                   float* __restrict__ h161,
                                                   float* __restrict__ h321) {
    __shared__ float P[4][ROWLEN];   // 4*1352*4 = 21632 B
    const int wave = threadIdx.x >> 6;
    const int lane = threadIdx.x & 63;
    const int row  = (blockIdx.x << 2) + wave;   // 0..4095 flat over images

    const float4* xr = reinterpret_cast<const float4*>(x + (size_t)row * W);
    float v[16];
    {
        float4 a0 = xr[(lane << 2) + 0];
        float4 a1 = xr[(lane << 2) + 1];
        float4 a2 = xr[(lane << 2) + 2];
        float4 a3 = xr[(lane << 2) + 3];
        v[0]=a0.x; v[1]=a0.y; v[2]=a0.z; v[3]=a0.w;
        v[4]=a1.x; v[5]=a1.y; v[6]=a1.z; v[7]=a1.w;
        v[8]=a2.x; v[9]=a2.y; v[10]=a2.z; v[11]=a2.w;
        v[12]=a3.x; v[13]=a3.y; v[14]=a3.z; v[15]=a3.w;
    }
    float s = 0.f;
#pragma unroll
    for (int j = 0; j < 16; ++j) { s += v[j]; v[j] = s; }
    float t = s;
#pragma unroll
    for (int d = 1; d < 64; d <<= 1) {
        float u = __shfl_up(t, d, 64);
        if (lane >= d) t += u;
    }
    const float off = t - s;           // exclusive prefix of lane totals
#pragma unroll
    for (int j = 0; j < 16; ++j) v[j] += off;
    const float tot = __shfl(t, 63, 64);

    float* rowP = P[wave];
    float4* Pr = reinterpret_cast<float4*>(rowP + PADL);
    Pr[(lane << 2) + 0] = make_float4(v[0], v[1], v[2], v[3]);
    Pr[(lane << 2) + 1] = make_float4(v[4], v[5], v[6], v[7]);
    Pr[(lane << 2) + 2] = make_float4(v[8], v[9], v[10], v[11]);
    Pr[(lane << 2) + 3] = make_float4(v[12], v[13], v[14], v[15]);
    // pads: quads 0..40 = 0 (left), quads 297..337 = tot (right)
    {
        float4* Pz = reinterpret_cast<float4*>(rowP);
        if (lane < 41) {
            Pz[lane]       = make_float4(0.f, 0.f, 0.f, 0.f);
            Pz[297 + lane] = make_float4(tot, tot, tot, tot);
        }
    }
    __syncthreads();

    const float* Pw = &P[wave][PADL];
    float* o161 = h161 + (size_t)row * W;
    float* o321 = h321 + (size_t)row * W;
#pragma unroll
    for (int k = 0; k < 16; ++k) {
        const int c = lane + (k << 6);
        const float s1 = Pw[c + 80]  - Pw[c - 81];
        const float s3 = Pw[c + 160] - Pw[c - 161];
        o161[c] = s1;
        o321[c] = s3;
    }
}

// ------------- Kernel 2: in-place per-segment column prefix + totals -------
// grid.x = img*seg*colblk (4*32*4=512), grid.y = buffer (0:h161, 1:h321).
__global__ __launch_bounds__(256) void vscan_kernel(float* __restrict__ h161,
                                                    float* __restrict__ h321,
                                                    float* __restrict__ Btot) {
    const int bx  = blockIdx.x;
    const int img = bx >> 7;
    const int b7  = bx & 127;
    const int seg = b7 >> 2;
    const int cb  = b7 & 3;
    const int col = (cb << 8) + threadIdx.x;
    const int r0  = seg << 5;

    float* p = (blockIdx.y ? h321 : h161) + ((size_t)img << 20) + col;
    float sum = 0.f;
#pragma unroll
    for (int jj = 0; jj < SEGR; jj += 8) {
        float a[8];
#pragma unroll
        for (int j = 0; j < 8; ++j) a[j] = p[(size_t)(r0 + jj + j) << 10];
#pragma unroll
        for (int j = 0; j < 8; ++j) { sum += a[j]; a[j] = sum; }
#pragma unroll
        for (int j = 0; j < 8; ++j) p[(size_t)(r0 + jj + j) << 10] = a[j];
    }
    Btot[((((size_t)blockIdx.y << 2) + img) << 15) + ((size_t)seg << 10) + col] = sum;
}

// ------------- Kernel 3: exclusive scan of segment totals per column -------
// 2 bufs x 4 imgs x 1024 cols = 8192 threads = 32 blocks x 256.
__global__ __launch_bounds__(256) void segscan_kernel(const float* __restrict__ Btot,
                                                      float* __restrict__ SP) {
    const int t = blockIdx.x * 256 + threadIdx.x;      // (buf*4+img)*1024 + col
    const size_t base = ((size_t)(t >> 10) << 15) + (t & 1023);
    const float* b = Btot + base;
    float* sp = SP + base;
    float off = 0.f;
#pragma unroll
    for (int sg = 0; sg < NSEG; ++sg) {
        const float v = b[(size_t)sg << 10];
        sp[(size_t)sg << 10] = off;
        off += v;
    }
}

// ------------- Kernel 4: final — window diffs of full column prefixes ------
// 512 threads = 2 rows x 256 quad-columns per block; rcp-based division.
__global__ __launch_bounds__(512) void final_kernel(const float* __restrict__ g161,
                                                    const float* __restrict__ g321,
                                                    const float* __restrict__ SP,
                                                    float* __restrict__ out) {
    const int img = blockIdx.x >> 9;
    const int r   = ((blockIdx.x & 511) << 1) + (threadIdx.x >> 8);
    const int c4  = threadIdx.x & 255;

    const float4* P1 = reinterpret_cast<const float4*>(g161 + ((size_t)img << 20));
    const float4* P3 = reinterpret_cast<const float4*>(g321 + ((size_t)img << 20));
    // SP float4 layout: [buf][img][NSEG][256] ; NSEG*256 = 1<<13 per (buf,img)
    const float4* SP1 = reinterpret_cast<const float4*>(SP) + ((size_t)img << 13);
    const float4* SP3 = reinterpret_cast<const float4*>(SP) + ((size_t)(IMG + img) << 13);

    const int hi1 = min(r + 80, H - 1),  lo1 = r - 81;
    const int hi3 = min(r + 160, H - 1), lo3 = r - 161;

    float4 f  = P1[((size_t)hi1 << 8) + c4];
    float4 fs = SP1[(((size_t)hi1 >> 5) << 8) + c4];
    float fx = f.x + fs.x, fy = f.y + fs.y, fz = f.z + fs.z, fw = f.w + fs.w;
    if (lo1 >= 0) {
        float4 g  = P1[((size_t)lo1 << 8) + c4];
        float4 gs = SP1[(((size_t)lo1 >> 5) << 8) + c4];
        fx -= g.x + gs.x; fy -= g.y + gs.y; fz -= g.z + gs.z; fw -= g.w + gs.w;
    }
    float4 a  = P3[((size_t)hi3 << 8) + c4];
    float4 as = SP3[(((size_t)hi3 >> 5) << 8) + c4];
    float ax = a.x + as.x, ay = a.y + as.y, az = a.z + as.z, aw = a.w + as.w;
    if (lo3 >= 0) {
        float4 g  = P3[((size_t)lo3 << 8) + c4];
        float4 gs = SP3[(((size_t)lo3 >> 5) << 8) + c4];
        ax -= g.x + gs.x; ay -= g.y + gs.y; az -= g.z + gs.z; aw -= g.w + gs.w;
    }

    const float SCALE = (float)(77120.0 / 46657.8);   // BG_AREA / FRONT_DIV
    float4 o;
    o.x = SCALE * fx * __builtin_amdgcn_rcpf(ax - fx);
    o.y = SCALE * fy * __builtin_amdgcn_rcpf(ay - fy);
    o.z = SCALE * fz * __builtin_amdgcn_rcpf(az - fz);
    o.w = SCALE * fw * __builtin_amdgcn_rcpf(aw - fw);
    reinterpret_cast<float4*>(out + ((size_t)img << 20) + ((size_t)r << 10))[c4] = o;
}

extern "C" void kernel_launch(void* const* d_in, const int* in_sizes, int n_in,
                              void* d_out, int out_size, void* d_ws, size_t ws_size,
                              hipStream_t stream) {
    const float* x = (const float*)d_in[0];
    float* outp = (float*)d_out;
    float* h161 = (float*)d_ws;                          // 16 MB
    float* h321 = h161 + (size_t)IMG * H * W;            // 16 MB
    float* Btot = h321 + (size_t)IMG * H * W;            // 1 MB (2*4*32*1024 fp32)
    float* SPb  = Btot + (size_t)2 * IMG * NSEG * W;     // 1 MB

    hbox_kernel<<<dim3((IMG * H) / 4), dim3(256), 0, stream>>>(x, h161, h321);
    vscan_kernel<<<dim3(512, 2), dim3(256), 0, stream>>>(h161, h321, Btot);
    segscan_kernel<<<dim3(32), dim3(256), 0, stream>>>(Btot, SPb);
    final_kernel<<<dim3(IMG * (H / 2)), dim3(512), 0, stream>>>(h161, h321, SPb, outp);
}